// Round 2
// baseline (2557.153 us; speedup 1.0000x reference)
//
#include <hip/hip_runtime.h>
#include <math.h>

#define EPSV 1e-5f

// Shapes (fixed): B=64, C=2048, H=24, W=8 -> L=192, M=B*L=12288
// D_in2=384, Dssm=192, N=16, R=6

// ---------------- LayerNorm + transpose (B,C,H,W) -> (B*L, C) ----------------
__global__ __launch_bounds__(256) void ln_kernel(
    const float* __restrict__ feat, const float* __restrict__ lnw,
    const float* __restrict__ lnb, float* __restrict__ fm)
{
  const int m = blockIdx.x;            // b*192 + l
  const int b = m / 192, l = m - b * 192;
  const float* src = feat + (size_t)b * (2048u * 192u) + l;
  const int tid = threadIdx.x;
  float v[8];
  float s = 0.f;
#pragma unroll
  for (int i = 0; i < 8; ++i) {
    const int c = tid + i * 256;
    v[i] = src[(size_t)c * 192];
    s += v[i];
  }
  __shared__ float red[8];
#pragma unroll
  for (int o = 32; o > 0; o >>= 1) s += __shfl_down(s, o, 64);
  if ((tid & 63) == 0) red[tid >> 6] = s;
  __syncthreads();
  const float mu = (red[0] + red[1] + red[2] + red[3]) * (1.f / 2048.f);
  float sq = 0.f;
#pragma unroll
  for (int i = 0; i < 8; ++i) { const float d = v[i] - mu; sq = fmaf(d, d, sq); }
#pragma unroll
  for (int o = 32; o > 0; o >>= 1) sq += __shfl_down(sq, o, 64);
  if ((tid & 63) == 0) red[4 + (tid >> 6)] = sq;
  __syncthreads();
  const float rstd = rsqrtf((red[4] + red[5] + red[6] + red[7]) * (1.f / 2048.f) + EPSV);
  float* dst = fm + (size_t)m * 2048;
#pragma unroll
  for (int i = 0; i < 8; ++i) {
    const int c = tid + i * 256;
    dst[c] = (v[i] - mu) * rstd * lnw[c] + lnb[c];
  }
}

// ---------------- Generic 64x64 tiled fp32 GEMM: C = A * B^T (+bias) ----------
// A: M x K row-major (lda). If B_KN: B is K x N row-major (ldb), else B is
// N x K row-major (ldb). M, N multiples of 64; K multiple of 16.
template<bool B_KN, bool HAS_BIAS>
__global__ __launch_bounds__(256) void gemm64(
    const float* __restrict__ A, const float* __restrict__ B,
    const float* __restrict__ bias, float* __restrict__ C,
    int M, int N, int K, int lda, int ldb, int ldc)
{
  __shared__ float As[16][68];
  __shared__ float Bs[16][68];
  const int tid = threadIdx.x;
  const int bm = blockIdx.y * 64, bn = blockIdx.x * 64;
  const int alm = tid >> 2, alk = (tid & 3) << 2;
  const int tx = tid & 15, ty = tid >> 4;
  float acc[4][4] = {};
  for (int k0 = 0; k0 < K; k0 += 16) {
    {
      const float4 va = *(const float4*)(A + (size_t)(bm + alm) * lda + k0 + alk);
      As[alk + 0][alm] = va.x; As[alk + 1][alm] = va.y;
      As[alk + 2][alm] = va.z; As[alk + 3][alm] = va.w;
    }
    if (B_KN) {
      const int kk = tid >> 4, n4 = (tid & 15) << 2;
      const float4 vb = *(const float4*)(B + (size_t)(k0 + kk) * ldb + bn + n4);
      *(float4*)&Bs[kk][n4] = vb;
    } else {
      const float4 vb = *(const float4*)(B + (size_t)(bn + alm) * ldb + k0 + alk);
      Bs[alk + 0][alm] = vb.x; Bs[alk + 1][alm] = vb.y;
      Bs[alk + 2][alm] = vb.z; Bs[alk + 3][alm] = vb.w;
    }
    __syncthreads();
#pragma unroll
    for (int k = 0; k < 16; ++k) {
      const float4 a4 = *(const float4*)&As[k][tx << 2];
      const float4 b4 = *(const float4*)&Bs[k][ty << 2];
      const float av[4] = {a4.x, a4.y, a4.z, a4.w};
      const float bv[4] = {b4.x, b4.y, b4.z, b4.w};
#pragma unroll
      for (int i = 0; i < 4; ++i)
#pragma unroll
        for (int j = 0; j < 4; ++j)
          acc[i][j] = fmaf(av[i], bv[j], acc[i][j]);
    }
    __syncthreads();
  }
  const int n0 = bn + (ty << 2);
  float bx = 0.f, by = 0.f, bz = 0.f, bw = 0.f;
  if (HAS_BIAS) { bx = bias[n0]; by = bias[n0 + 1]; bz = bias[n0 + 2]; bw = bias[n0 + 3]; }
#pragma unroll
  for (int i = 0; i < 4; ++i) {
    const int m = bm + (tx << 2) + i;
    float4 o;
    o.x = acc[i][0] + bx; o.y = acc[i][1] + by;
    o.z = acc[i][2] + bz; o.w = acc[i][3] + bw;
    *(float4*)(C + (size_t)m * ldc + n0) = o;
  }
}

// ---------------- x_proj + dt: per row m compute x_dbl(38), dts(192), Bs, Cs --
__global__ __launch_bounds__(64) void xproj_kernel(
    const float* __restrict__ xz, const float* __restrict__ xpw,
    const float* __restrict__ dtw, float* __restrict__ dts,
    float* __restrict__ Bsb, float* __restrict__ Csb)
{
  const int m = blockIdx.x, tid = threadIdx.x;
  __shared__ float xrow[192];
  __shared__ float xdbl[38];
  const float* src = xz + (size_t)m * 384;   // x = first 192 of xz row
#pragma unroll
  for (int i = 0; i < 3; ++i) xrow[tid + i * 64] = src[tid + i * 64];
  __syncthreads();
  if (tid < 38) {
    float a = 0.f;
    const float* wr = xpw + tid * 192;
    for (int d = 0; d < 192; ++d) a = fmaf(xrow[d], wr[d], a);
    xdbl[tid] = a;
  }
  __syncthreads();
  if (tid < 16) Bsb[(size_t)m * 16 + tid] = xdbl[6 + tid];
  else if (tid < 32) Csb[(size_t)m * 16 + (tid - 16)] = xdbl[22 + (tid - 16)];
#pragma unroll
  for (int i = 0; i < 3; ++i) {
    const int d = tid + i * 64;
    const float* w = dtw + d * 6;
    float a = xdbl[0] * w[0] + xdbl[1] * w[1] + xdbl[2] * w[2]
            + xdbl[3] * w[3] + xdbl[4] * w[4] + xdbl[5] * w[5];
    dts[(size_t)m * 192 + d] = (a > 20.f) ? a : log1pf(__expf(a));  // softplus
  }
}

// ---------------- bidirectional selective scan, fused D-term + silu(z) -------
// grid = B * (192/16) = 768 blocks, 256 threads: tid = d_local*16 + n
// NOTE: reference adds x*Ds in BOTH scan directions -> total term is 2*x*Ds.
__global__ __launch_bounds__(256) void scan_kernel(
    const float* __restrict__ xz, const float* __restrict__ dts,
    const float* __restrict__ Bsb, const float* __restrict__ Csb,
    const float* __restrict__ A_logs, const float* __restrict__ Ds,
    float* __restrict__ ssm)
{
  const int tid = threadIdx.x;
  const int n = tid & 15, dl = tid >> 4;
  const int b = blockIdx.x / 12, dblk = blockIdx.x - b * 12;
  const int d = dblk * 16 + dl;
  const float Acoef = -expf(A_logs[d * 16 + n]);
  const float Dd = Ds[d];
  const size_t rbase = (size_t)b * 192;
  float u = 0.f;
  for (int l = 0; l < 192; ++l) {
    const size_t row = rbase + l;
    const float dt = dts[row * 192 + d];
    const float xv = xz[row * 384 + d];
    const float Bv = Bsb[row * 16 + n];
    const float Cv = Csb[row * 16 + n];
    const float a = __expf(dt * Acoef);
    u = fmaf(a, u, dt * Bv * xv);
    float y = u * Cv;
    y += __shfl_xor(y, 1, 16); y += __shfl_xor(y, 2, 16);
    y += __shfl_xor(y, 4, 16); y += __shfl_xor(y, 8, 16);
    if (n == 0) ssm[row * 192 + d] = y;     // yf
  }
  u = 0.f;
  for (int l = 191; l >= 0; --l) {
    const size_t row = rbase + l;
    const float dt = dts[row * 192 + d];
    const float xv = xz[row * 384 + d];
    const float Bv = Bsb[row * 16 + n];
    const float Cv = Csb[row * 16 + n];
    const float a = __expf(dt * Acoef);
    u = fmaf(a, u, dt * Bv * xv);
    float y = u * Cv;
    y += __shfl_xor(y, 1, 16); y += __shfl_xor(y, 2, 16);
    y += __shfl_xor(y, 4, 16); y += __shfl_xor(y, 8, 16);
    if (n == 0) {
      const float zv = xz[row * 384 + 192 + d];
      const float sil = zv / (1.f + __expf(-zv));
      const float tot = ssm[row * 192 + d] + y + 2.f * xv * Dd;  // D-term twice!
      ssm[row * 192 + d] = tot * sil;
    }
  }
}

// ---------------- BN prep: scale/shift per output channel o ------------------
__global__ __launch_bounds__(64) void prep_kernel(
    const float* __restrict__ mo_w, const float* __restrict__ mo_b,
    const float* __restrict__ out_b,
    const float* __restrict__ bn_w, const float* __restrict__ bn_b,
    const float* __restrict__ bn_rm, const float* __restrict__ bn_rv,
    float* __restrict__ scale, float* __restrict__ shift)
{
  const int o = blockIdx.x, tid = threadIdx.x;
  float s = 0.f;
  for (int c = tid; c < 2048; c += 64) s = fmaf(mo_w[(size_t)o * 2048 + c], out_b[c], s);
#pragma unroll
  for (int off = 32; off > 0; off >>= 1) s += __shfl_down(s, off, 64);
  if (tid == 0) {
    const float b2 = s + mo_b[o];
    const float sc = bn_w[o] * rsqrtf(bn_rv[o] + EPSV);
    scale[o] = sc;
    shift[o] = (b2 - bn_rm[o]) * sc + bn_b[o];
  }
}

// ---------------- Final fused GEMM: out = relu(bn(fm@mo_w^T + ssm@W2^T)) -----
// with transposed store (B,L,C) -> (B,C,H,W)
__global__ __launch_bounds__(256) void gemm3_kernel(
    const float* __restrict__ fm, const float* __restrict__ mo_w,
    const float* __restrict__ ssm, const float* __restrict__ W2,
    const float* __restrict__ scale, const float* __restrict__ shift,
    float* __restrict__ out)
{
  __shared__ float As[16][68];
  __shared__ float Bs[16][68];
  const int tid = threadIdx.x;
  const int bm = blockIdx.y * 64, bn = blockIdx.x * 64;
  const int alm = tid >> 2, alk = (tid & 3) << 2;
  const int tx = tid & 15, ty = tid >> 4;
  float acc[4][4] = {};
  // K1 = 2048 over fm / mo_w
  for (int k0 = 0; k0 < 2048; k0 += 16) {
    {
      const float4 va = *(const float4*)(fm + (size_t)(bm + alm) * 2048 + k0 + alk);
      As[alk + 0][alm] = va.x; As[alk + 1][alm] = va.y;
      As[alk + 2][alm] = va.z; As[alk + 3][alm] = va.w;
      const float4 vb = *(const float4*)(mo_w + (size_t)(bn + alm) * 2048 + k0 + alk);
      Bs[alk + 0][alm] = vb.x; Bs[alk + 1][alm] = vb.y;
      Bs[alk + 2][alm] = vb.z; Bs[alk + 3][alm] = vb.w;
    }
    __syncthreads();
#pragma unroll
    for (int k = 0; k < 16; ++k) {
      const float4 a4 = *(const float4*)&As[k][tx << 2];
      const float4 b4 = *(const float4*)&Bs[k][ty << 2];
      const float av[4] = {a4.x, a4.y, a4.z, a4.w};
      const float bv[4] = {b4.x, b4.y, b4.z, b4.w};
#pragma unroll
      for (int i = 0; i < 4; ++i)
#pragma unroll
        for (int j = 0; j < 4; ++j)
          acc[i][j] = fmaf(av[i], bv[j], acc[i][j]);
    }
    __syncthreads();
  }
  // K2 = 192 over ssm / W2
  for (int k0 = 0; k0 < 192; k0 += 16) {
    {
      const float4 va = *(const float4*)(ssm + (size_t)(bm + alm) * 192 + k0 + alk);
      As[alk + 0][alm] = va.x; As[alk + 1][alm] = va.y;
      As[alk + 2][alm] = va.z; As[alk + 3][alm] = va.w;
      const float4 vb = *(const float4*)(W2 + (size_t)(bn + alm) * 192 + k0 + alk);
      Bs[alk + 0][alm] = vb.x; Bs[alk + 1][alm] = vb.y;
      Bs[alk + 2][alm] = vb.z; Bs[alk + 3][alm] = vb.w;
    }
    __syncthreads();
#pragma unroll
    for (int k = 0; k < 16; ++k) {
      const float4 a4 = *(const float4*)&As[k][tx << 2];
      const float4 b4 = *(const float4*)&Bs[k][ty << 2];
      const float av[4] = {a4.x, a4.y, a4.z, a4.w};
      const float bv[4] = {b4.x, b4.y, b4.z, b4.w};
#pragma unroll
      for (int i = 0; i < 4; ++i)
#pragma unroll
        for (int j = 0; j < 4; ++j)
          acc[i][j] = fmaf(av[i], bv[j], acc[i][j]);
    }
    __syncthreads();
  }
  // epilogue: BN + relu + transposed store. 64-row tile lies within one b.
  const int b = bm / 192;
  const int l0 = bm - b * 192;
#pragma unroll
  for (int j = 0; j < 4; ++j) {
    const int n = bn + (ty << 2) + j;
    const float sc = scale[n], sh = shift[n];
    float* op = out + ((size_t)b * 2048 + n) * 192 + l0 + (tx << 2);
#pragma unroll
    for (int i = 0; i < 4; ++i) {
      op[i] = fmaxf(fmaf(acc[i][j], sc, sh), 0.f);
    }
  }
}

extern "C" void kernel_launch(void* const* d_in, const int* in_sizes, int n_in,
                              void* d_out, int out_size, void* d_ws, size_t ws_size,
                              hipStream_t stream) {
  const float* feat  = (const float*)d_in[0];
  const float* ln_w  = (const float*)d_in[1];
  const float* ln_b  = (const float*)d_in[2];
  const float* in_w  = (const float*)d_in[3];
  const float* in_b  = (const float*)d_in[4];
  const float* xpw   = (const float*)d_in[5];
  const float* dtw   = (const float*)d_in[6];
  const float* A_logs= (const float*)d_in[7];
  const float* Ds    = (const float*)d_in[8];
  const float* out_w = (const float*)d_in[9];
  const float* out_b = (const float*)d_in[10];
  const float* mo_w  = (const float*)d_in[11];
  const float* mo_b  = (const float*)d_in[12];
  const float* bn_w  = (const float*)d_in[13];
  const float* bn_b  = (const float*)d_in[14];
  const float* bn_rm = (const float*)d_in[15];
  const float* bn_rv = (const float*)d_in[16];
  float* out = (float*)d_out;
  float* ws  = (float*)d_ws;

  // workspace layout (floats); total 35,393,536 floats = 141.6 MB
  float* fm    = ws;                   // 12288*2048
  float* xz    = fm    + 25165824;     // 12288*384
  float* dts   = xz    + 4718592;      // 12288*192
  float* Bsb   = dts   + 2359296;      // 12288*16
  float* Csb   = Bsb   + 196608;       // 12288*16
  float* ssm   = Csb   + 196608;       // 12288*192
  float* W2    = ssm   + 2359296;      // 2048*192
  float* scale = W2    + 393216;       // 2048
  float* shift = scale + 2048;         // 2048
  if (ws_size < (size_t)35393536 * sizeof(float)) return;

  ln_kernel<<<12288, 256, 0, stream>>>(feat, ln_w, ln_b, fm);
  gemm64<false, true><<<dim3(6, 192), 256, 0, stream>>>(
      fm, in_w, in_b, xz, 12288, 384, 2048, 2048, 2048, 384);
  xproj_kernel<<<12288, 64, 0, stream>>>(xz, xpw, dtw, dts, Bsb, Csb);
  scan_kernel<<<768, 256, 0, stream>>>(xz, dts, Bsb, Csb, A_logs, Ds, ssm);
  gemm64<true, false><<<dim3(3, 32), 256, 0, stream>>>(
      mo_w, out_w, nullptr, W2, 2048, 192, 2048, 2048, 192, 192);
  prep_kernel<<<2048, 64, 0, stream>>>(mo_w, mo_b, out_b, bn_w, bn_b, bn_rm, bn_rv, scale, shift);
  gemm3_kernel<<<dim3(32, 192), 256, 0, stream>>>(fm, mo_w, ssm, W2, scale, shift, out);
}

// Round 3
// 884.975 us; speedup vs baseline: 2.8895x; 2.8895x over previous
//
#include <hip/hip_runtime.h>
#include <math.h>

#define EPSV 1e-5f

// Shapes (fixed): B=64, C=2048, H=24, W=8 -> L=192, M=B*L=12288
// D_in2=384, Dssm=192, N=16, R=6

typedef __attribute__((ext_vector_type(8))) __bf16 bf16x8;
typedef __attribute__((ext_vector_type(4))) float f32x4;

__device__ __forceinline__ ushort f2bf(float f) {
  union { float f; unsigned u; } v; v.f = f;
  const unsigned r = v.u + 0x7fffu + ((v.u >> 16) & 1u);  // RNE
  return (ushort)(r >> 16);
}
__device__ __forceinline__ float bf2f(ushort h) {
  union { unsigned u; float f; } v; v.u = ((unsigned)h) << 16;
  return v.f;
}

// async 16B/lane global->LDS: LDS dest = wave-uniform base + lane*16
#define GLOAD16(G, L) __builtin_amdgcn_global_load_lds( \
    (__attribute__((address_space(1))) void*)(G), \
    (__attribute__((address_space(3))) void*)(L), 16, 0, 0)

// ---------------- fp32 -> bf16 convert ----------------
__global__ __launch_bounds__(256) void cvt_kernel(
    const float* __restrict__ s, ushort* __restrict__ d, int n)
{
  const int i = (blockIdx.x * 256 + threadIdx.x) * 4;
  if (i + 3 < n) {
    const float4 v = *(const float4*)(s + i);
    ushort4 o;
    o.x = f2bf(v.x); o.y = f2bf(v.y); o.z = f2bf(v.z); o.w = f2bf(v.w);
    *(ushort4*)(d + i) = o;
  }
}

// ---------------- LN stats: coalesced partial sums + atomics ----------------
// grid (64, 16): (b, c-chunk of 128). threads 0..191 = l.
__global__ __launch_bounds__(256) void ln_stats(
    const float* __restrict__ feat, float* __restrict__ sums)
{
  const int b = blockIdx.x, c0 = blockIdx.y * 128;
  const int l = threadIdx.x;
  if (l >= 192) return;
  const float* p = feat + ((size_t)b * 2048 + c0) * 192 + l;
  float s = 0.f, sq = 0.f;
  for (int c = 0; c < 128; ++c) { const float v = p[(size_t)c * 192]; s += v; sq = fmaf(v, v, sq); }
  atomicAdd(&sums[(b * 192 + l) * 2], s);
  atomicAdd(&sums[(b * 192 + l) * 2 + 1], sq);
}

// ---------------- LN apply + transpose -> bf16 fm (B*L, C) ----------------
// grid (64, 32, 3): (b, c-tile 64, l-tile 64). 256 threads.
__global__ __launch_bounds__(256) void ln_apply(
    const float* __restrict__ feat, const float* __restrict__ sums,
    const float* __restrict__ lnw, const float* __restrict__ lnb,
    ushort* __restrict__ fm)
{
  __shared__ float tile[64][65];
  __shared__ float smu[64], srs[64];
  const int b = blockIdx.x, c0 = blockIdx.y * 64, l0 = blockIdx.z * 64;
  const int tl = threadIdx.x & 63, tg = threadIdx.x >> 6;
#pragma unroll
  for (int r = 0; r < 16; ++r) {
    const int c = r * 4 + tg;
    tile[c][tl] = feat[((size_t)b * 2048 + c0 + c) * 192 + l0 + tl];
  }
  if (threadIdx.x < 64) {
    const float s  = sums[(b * 192 + l0 + threadIdx.x) * 2];
    const float sq = sums[(b * 192 + l0 + threadIdx.x) * 2 + 1];
    const float mu = s * (1.f / 2048.f);
    smu[threadIdx.x] = mu;
    srs[threadIdx.x] = rsqrtf(sq * (1.f / 2048.f) - mu * mu + EPSV);
  }
  __syncthreads();
  const float w = lnw[c0 + tl], bb = lnb[c0 + tl];
#pragma unroll
  for (int r = 0; r < 16; ++r) {
    const int ll = r * 4 + tg;
    fm[((size_t)(b * 192 + l0 + ll)) * 2048 + c0 + tl] =
        f2bf((tile[tl][ll] - smu[ll]) * srs[ll] * w + bb);
  }
}

// ---------------- MFMA K-phase: 128x128 tile, BK=32, 16x16x32 bf16 ----------
__device__ __forceinline__ void mfma_phase(
    const ushort* __restrict__ Ag, int lda,
    const ushort* __restrict__ Bg, int ldb, int K,
    int bm, int bn, int tid, ushort* As, ushort* Bs, f32x4 acc[4][4])
{
  const int lane = tid & 63, wave = tid >> 6;
  const int wm = (wave & 1) << 6, wn = (wave >> 1) << 6;
  const int fr = lane & 15, q = lane >> 4;
  const int r0 = tid >> 2, kc = (tid & 3) << 3;   // staging row / k-chunk
  const int lb = (tid & 192) * 8;                 // wave-uniform LDS base (ushorts)
  for (int k0 = 0; k0 < K; k0 += 32) {
    __syncthreads();
    GLOAD16(Ag + (size_t)(bm + r0) * lda + k0 + kc,      As + lb);
    GLOAD16(Ag + (size_t)(bm + 64 + r0) * lda + k0 + kc, As + 2048 + lb);
    GLOAD16(Bg + (size_t)(bn + r0) * ldb + k0 + kc,      Bs + lb);
    GLOAD16(Bg + (size_t)(bn + 64 + r0) * ldb + k0 + kc, Bs + 2048 + lb);
    __syncthreads();
    bf16x8 af[4], bfr[4];
#pragma unroll
    for (int i = 0; i < 4; ++i) {
      af[i]  = *(const bf16x8*)&As[(wm + i * 16 + fr) * 32 + q * 8];
      bfr[i] = *(const bf16x8*)&Bs[(wn + i * 16 + fr) * 32 + q * 8];
    }
#pragma unroll
    for (int i = 0; i < 4; ++i)
#pragma unroll
      for (int j = 0; j < 4; ++j)
        acc[i][j] = __builtin_amdgcn_mfma_f32_16x16x32_bf16(af[i], bfr[j], acc[i][j], 0, 0, 0);
  }
}

// MODE 0: xz = A1*B1^T + bias(p0), fp32 row-major ldc=384.
// MODE 1: out = relu((A1*B1^T + A2*B2^T)*scale(p0) + shift(p1)), transposed store.
template<int MODE>
__global__ __launch_bounds__(256) void mfma_gemm(
    const ushort* __restrict__ A1, const ushort* __restrict__ B1,
    const ushort* __restrict__ A2, const ushort* __restrict__ B2,
    const float* __restrict__ p0, const float* __restrict__ p1,
    float* __restrict__ out)
{
  __shared__ ushort As[4096], Bs[4096];
  const int tid = threadIdx.x;
  const int bm = blockIdx.y * 128, bn = blockIdx.x * 128;
  f32x4 acc[4][4];
#pragma unroll
  for (int i = 0; i < 4; ++i)
#pragma unroll
    for (int j = 0; j < 4; ++j) acc[i][j] = (f32x4)(0.f);

  mfma_phase(A1, 2048, B1, 2048, 2048, bm, bn, tid, As, Bs, acc);
  if (MODE == 1)
    mfma_phase(A2, 192, B2, 192, 192, bm, bn, tid, As, Bs, acc);

  const int lane = tid & 63, wave = tid >> 6;
  const int wm = (wave & 1) << 6, wn = (wave >> 1) << 6;
  const int fr = lane & 15, q = lane >> 4;
  if (MODE == 0) {
#pragma unroll
    for (int mi = 0; mi < 4; ++mi) {
      const int m0 = bm + wm + mi * 16 + q * 4;
#pragma unroll
      for (int ni = 0; ni < 4; ++ni) {
        const int n = bn + wn + ni * 16 + fr;
        const float bias = p0[n];
#pragma unroll
        for (int r = 0; r < 4; ++r)
          out[(size_t)(m0 + r) * 384 + n] = acc[mi][ni][r] + bias;
      }
    }
  } else {
#pragma unroll
    for (int mi = 0; mi < 4; ++mi) {
      const int m0 = bm + wm + mi * 16 + q * 4;
      const int b = m0 / 192, l0 = m0 - b * 192;   // quad never straddles b
#pragma unroll
      for (int ni = 0; ni < 4; ++ni) {
        const int n = bn + wn + ni * 16 + fr;
        const float sc = p0[n], sh = p1[n];
        float4 o;
        o.x = fmaxf(fmaf(acc[mi][ni][0], sc, sh), 0.f);
        o.y = fmaxf(fmaf(acc[mi][ni][1], sc, sh), 0.f);
        o.z = fmaxf(fmaf(acc[mi][ni][2], sc, sh), 0.f);
        o.w = fmaxf(fmaf(acc[mi][ni][3], sc, sh), 0.f);
        *(float4*)(out + ((size_t)b * 2048 + n) * 192 + l0) = o;
      }
    }
  }
}

// ---------------- Generic 64x64 tiled fp32 GEMM (kept for W2) ----------------
template<bool B_KN, bool HAS_BIAS>
__global__ __launch_bounds__(256) void gemm64(
    const float* __restrict__ A, const float* __restrict__ B,
    const float* __restrict__ bias, float* __restrict__ C,
    int M, int N, int K, int lda, int ldb, int ldc)
{
  __shared__ float Asx[16][68];
  __shared__ float Bsx[16][68];
  const int tid = threadIdx.x;
  const int bm = blockIdx.y * 64, bn = blockIdx.x * 64;
  const int alm = tid >> 2, alk = (tid & 3) << 2;
  const int tx = tid & 15, ty = tid >> 4;
  float acc[4][4] = {};
  for (int k0 = 0; k0 < K; k0 += 16) {
    {
      const float4 va = *(const float4*)(A + (size_t)(bm + alm) * lda + k0 + alk);
      Asx[alk + 0][alm] = va.x; Asx[alk + 1][alm] = va.y;
      Asx[alk + 2][alm] = va.z; Asx[alk + 3][alm] = va.w;
    }
    if (B_KN) {
      const int kk = tid >> 4, n4 = (tid & 15) << 2;
      const float4 vb = *(const float4*)(B + (size_t)(k0 + kk) * ldb + bn + n4);
      *(float4*)&Bsx[kk][n4] = vb;
    } else {
      const float4 vb = *(const float4*)(B + (size_t)(bn + alm) * ldb + k0 + alk);
      Bsx[alk + 0][alm] = vb.x; Bsx[alk + 1][alm] = vb.y;
      Bsx[alk + 2][alm] = vb.z; Bsx[alk + 3][alm] = vb.w;
    }
    __syncthreads();
#pragma unroll
    for (int k = 0; k < 16; ++k) {
      const float4 a4 = *(const float4*)&Asx[k][tx << 2];
      const float4 b4 = *(const float4*)&Bsx[k][ty << 2];
      const float av[4] = {a4.x, a4.y, a4.z, a4.w};
      const float bv[4] = {b4.x, b4.y, b4.z, b4.w};
#pragma unroll
      for (int i = 0; i < 4; ++i)
#pragma unroll
        for (int j = 0; j < 4; ++j)
          acc[i][j] = fmaf(av[i], bv[j], acc[i][j]);
    }
    __syncthreads();
  }
  const int n0 = bn + (ty << 2);
  float bx = 0.f, by = 0.f, bz = 0.f, bw = 0.f;
  if (HAS_BIAS) { bx = bias[n0]; by = bias[n0 + 1]; bz = bias[n0 + 2]; bw = bias[n0 + 3]; }
#pragma unroll
  for (int i = 0; i < 4; ++i) {
    const int m = bm + (tx << 2) + i;
    float4 o;
    o.x = acc[i][0] + bx; o.y = acc[i][1] + by;
    o.z = acc[i][2] + bz; o.w = acc[i][3] + bw;
    *(float4*)(C + (size_t)m * ldc + n0) = o;
  }
}

// ---------------- x_proj + dt ----------------
__global__ __launch_bounds__(64) void xproj_kernel(
    const float* __restrict__ xz, const float* __restrict__ xpw,
    const float* __restrict__ dtw, float* __restrict__ dts,
    float* __restrict__ Bsb, float* __restrict__ Csb)
{
  const int m = blockIdx.x, tid = threadIdx.x;
  __shared__ float xrow[192];
  __shared__ float xdbl[38];
  const float* src = xz + (size_t)m * 384;
#pragma unroll
  for (int i = 0; i < 3; ++i) xrow[tid + i * 64] = src[tid + i * 64];
  __syncthreads();
  if (tid < 38) {
    float a = 0.f;
    const float* wr = xpw + tid * 192;
    for (int d = 0; d < 192; ++d) a = fmaf(xrow[d], wr[d], a);
    xdbl[tid] = a;
  }
  __syncthreads();
  if (tid < 16) Bsb[(size_t)m * 16 + tid] = xdbl[6 + tid];
  else if (tid < 32) Csb[(size_t)m * 16 + (tid - 16)] = xdbl[22 + (tid - 16)];
#pragma unroll
  for (int i = 0; i < 3; ++i) {
    const int d = tid + i * 64;
    const float* w = dtw + d * 6;
    float a = xdbl[0] * w[0] + xdbl[1] * w[1] + xdbl[2] * w[2]
            + xdbl[3] * w[3] + xdbl[4] * w[4] + xdbl[5] * w[5];
    dts[(size_t)m * 192 + d] = (a > 20.f) ? a : log1pf(__expf(a));
  }
}

// ---------------- bidirectional selective scan -> bf16 ssm ----------------
__global__ __launch_bounds__(256) void scan_kernel(
    const float* __restrict__ xz, const float* __restrict__ dts,
    const float* __restrict__ Bsb, const float* __restrict__ Csb,
    const float* __restrict__ A_logs, const float* __restrict__ Ds,
    ushort* __restrict__ ssm)
{
  const int tid = threadIdx.x;
  const int n = tid & 15, dl = tid >> 4;
  const int b = blockIdx.x / 12, dblk = blockIdx.x - b * 12;
  const int d = dblk * 16 + dl;
  const float Acoef = -expf(A_logs[d * 16 + n]);
  const float Dd = Ds[d];
  const size_t rbase = (size_t)b * 192;
  float u = 0.f;
  for (int l = 0; l < 192; ++l) {
    const size_t row = rbase + l;
    const float dt = dts[row * 192 + d];
    const float xv = xz[row * 384 + d];
    const float Bv = Bsb[row * 16 + n];
    const float Cv = Csb[row * 16 + n];
    const float a = __expf(dt * Acoef);
    u = fmaf(a, u, dt * Bv * xv);
    float y = u * Cv;
    y += __shfl_xor(y, 1, 16); y += __shfl_xor(y, 2, 16);
    y += __shfl_xor(y, 4, 16); y += __shfl_xor(y, 8, 16);
    if (n == 0) ssm[row * 192 + d] = f2bf(y);
  }
  u = 0.f;
  for (int l = 191; l >= 0; --l) {
    const size_t row = rbase + l;
    const float dt = dts[row * 192 + d];
    const float xv = xz[row * 384 + d];
    const float Bv = Bsb[row * 16 + n];
    const float Cv = Csb[row * 16 + n];
    const float a = __expf(dt * Acoef);
    u = fmaf(a, u, dt * Bv * xv);
    float y = u * Cv;
    y += __shfl_xor(y, 1, 16); y += __shfl_xor(y, 2, 16);
    y += __shfl_xor(y, 4, 16); y += __shfl_xor(y, 8, 16);
    if (n == 0) {
      const float zv = xz[row * 384 + 192 + d];
      const float sil = zv / (1.f + __expf(-zv));
      const float tot = bf2f(ssm[row * 192 + d]) + y + 2.f * xv * Dd;  // D-term x2
      ssm[row * 192 + d] = f2bf(tot * sil);
    }
  }
}

// ---------------- BN prep ----------------
__global__ __launch_bounds__(64) void prep_kernel(
    const float* __restrict__ mo_w, const float* __restrict__ mo_b,
    const float* __restrict__ out_b,
    const float* __restrict__ bn_w, const float* __restrict__ bn_b,
    const float* __restrict__ bn_rm, const float* __restrict__ bn_rv,
    float* __restrict__ scale, float* __restrict__ shift)
{
  const int o = blockIdx.x, tid = threadIdx.x;
  float s = 0.f;
  for (int c = tid; c < 2048; c += 64) s = fmaf(mo_w[(size_t)o * 2048 + c], out_b[c], s);
#pragma unroll
  for (int off = 32; off > 0; off >>= 1) s += __shfl_down(s, off, 64);
  if (tid == 0) {
    const float b2 = s + mo_b[o];
    const float sc = bn_w[o] * rsqrtf(bn_rv[o] + EPSV);
    scale[o] = sc;
    shift[o] = (b2 - bn_rm[o]) * sc + bn_b[o];
  }
}

extern "C" void kernel_launch(void* const* d_in, const int* in_sizes, int n_in,
                              void* d_out, int out_size, void* d_ws, size_t ws_size,
                              hipStream_t stream) {
  const float* feat  = (const float*)d_in[0];
  const float* ln_w  = (const float*)d_in[1];
  const float* ln_b  = (const float*)d_in[2];
  const float* in_w  = (const float*)d_in[3];
  const float* in_b  = (const float*)d_in[4];
  const float* xpw   = (const float*)d_in[5];
  const float* dtw   = (const float*)d_in[6];
  const float* A_logs= (const float*)d_in[7];
  const float* Ds    = (const float*)d_in[8];
  const float* out_w = (const float*)d_in[9];
  const float* out_b = (const float*)d_in[10];
  const float* mo_w  = (const float*)d_in[11];
  const float* mo_b  = (const float*)d_in[12];
  const float* bn_w  = (const float*)d_in[13];
  const float* bn_b  = (const float*)d_in[14];
  const float* bn_rm = (const float*)d_in[15];
  const float* bn_rv = (const float*)d_in[16];
  float* out = (float*)d_out;

  // ---- workspace layout (bytes) ----
  uint8_t* p = (uint8_t*)d_ws;
  ushort* fm_b  = (ushort*)p; p += (size_t)12288 * 2048 * 2;  // 50331648
  float*  xz    = (float*)p;  p += (size_t)12288 * 384 * 4;   // 18874368
  float*  dts   = (float*)p;  p += (size_t)12288 * 192 * 4;   // 9437184
  float*  Bsb   = (float*)p;  p += (size_t)12288 * 16 * 4;    // 786432
  float*  Csb   = (float*)p;  p += (size_t)12288 * 16 * 4;    // 786432
  ushort* ssm_b = (ushort*)p; p += (size_t)12288 * 192 * 2;   // 4718592
  float*  W2    = (float*)p;  p += (size_t)2048 * 192 * 4;    // 1572864
  ushort* W2b   = (ushort*)p; p += (size_t)2048 * 192 * 2;    // 786432
  ushort* mo_wb = (ushort*)p; p += (size_t)2048 * 2048 * 2;   // 8388608
  ushort* in_wb = (ushort*)p; p += (size_t)384 * 2048 * 2;    // 1572864
  float*  scale = (float*)p;  p += 2048 * 4;
  float*  shift = (float*)p;  p += 2048 * 4;
  float*  sums  = (float*)p;  p += (size_t)64 * 192 * 2 * 4;  // 98304
  if ((size_t)(p - (uint8_t*)d_ws) > ws_size) return;

  // weights -> bf16
  cvt_kernel<<<4096, 256, 0, stream>>>(mo_w, mo_wb, 2048 * 2048);
  cvt_kernel<<<768, 256, 0, stream>>>(in_w, in_wb, 384 * 2048);

  // LN (stats + apply/transpose -> bf16 fm)
  hipMemsetAsync(sums, 0, (size_t)64 * 192 * 2 * 4, stream);
  ln_stats<<<dim3(64, 16), 256, 0, stream>>>(feat, sums);
  ln_apply<<<dim3(64, 32, 3), 256, 0, stream>>>(feat, sums, ln_w, ln_b, fm_b);

  // GEMM1: xz = fm @ in_w^T + in_b   (M=12288, N=384, K=2048)
  mfma_gemm<0><<<dim3(3, 96), 256, 0, stream>>>(
      fm_b, in_wb, nullptr, nullptr, in_b, nullptr, xz);

  xproj_kernel<<<12288, 64, 0, stream>>>(xz, xpw, dtw, dts, Bsb, Csb);
  scan_kernel<<<768, 256, 0, stream>>>(xz, dts, Bsb, Csb, A_logs, Ds, ssm_b);

  // W2 = mo_w @ out_w (fp32), then bf16
  gemm64<true, false><<<dim3(3, 32), 256, 0, stream>>>(
      mo_w, out_w, nullptr, W2, 2048, 192, 2048, 2048, 192, 192);
  cvt_kernel<<<384, 256, 0, stream>>>(W2, W2b, 2048 * 192);
  prep_kernel<<<2048, 64, 0, stream>>>(mo_w, mo_b, out_b, bn_w, bn_b, bn_rm, bn_rv, scale, shift);

  // Final: out = relu(bn(fm@mo_w^T + ssm@W2^T)), transposed store
  mfma_gemm<1><<<dim3(16, 96), 256, 0, stream>>>(
      fm_b, mo_wb, ssm_b, W2b, scale, shift, out);
}

// Round 4
// 720.163 us; speedup vs baseline: 3.5508x; 1.2289x over previous
//
#include <hip/hip_runtime.h>
#include <math.h>

#define EPSV 1e-5f

// Shapes (fixed): B=64, C=2048, H=24, W=8 -> L=192, M=B*L=12288
// D_in2=384, Dssm=192, N=16, R=6

typedef __attribute__((ext_vector_type(8))) __bf16 bf16x8;
typedef __attribute__((ext_vector_type(4))) float f32x4;

__device__ __forceinline__ ushort f2bf(float f) {
  union { float f; unsigned u; } v; v.f = f;
  const unsigned r = v.u + 0x7fffu + ((v.u >> 16) & 1u);  // RNE
  return (ushort)(r >> 16);
}

// async 16B/lane global->LDS: LDS dest = wave-uniform base + lane*16
#define GLOAD16(G, L) __builtin_amdgcn_global_load_lds( \
    (__attribute__((address_space(1))) void*)(G), \
    (__attribute__((address_space(3))) void*)(L), 16, 0, 0)

// ---------------- fp32 -> bf16 convert ----------------
__global__ __launch_bounds__(256) void cvt_kernel(
    const float* __restrict__ s, ushort* __restrict__ d, int n)
{
  const int i = (blockIdx.x * 256 + threadIdx.x) * 4;
  if (i + 3 < n) {
    const float4 v = *(const float4*)(s + i);
    ushort4 o;
    o.x = f2bf(v.x); o.y = f2bf(v.y); o.z = f2bf(v.z); o.w = f2bf(v.w);
    *(ushort4*)(d + i) = o;
  }
}

// ---------------- transpose out_w (2048x192) -> bf16 out_wT (256x2048, pad 0) --
// grid (32, 3): c-tile 64, d-tile 64. 256 threads.
__global__ __launch_bounds__(256) void transpose_w(
    const float* __restrict__ w, ushort* __restrict__ wT)
{
  __shared__ float t[64][65];
  const int c0 = blockIdx.x * 64, d0 = blockIdx.y * 64;
  const int tl = threadIdx.x & 63, tg = threadIdx.x >> 6;
#pragma unroll
  for (int r = 0; r < 16; ++r) {
    const int c = r * 4 + tg;
    t[c][tl] = w[(size_t)(c0 + c) * 192 + d0 + tl];
  }
  __syncthreads();
#pragma unroll
  for (int r = 0; r < 16; ++r) {
    const int d = r * 4 + tg;
    wT[(size_t)(d0 + d) * 2048 + c0 + tl] = f2bf(t[tl][d]);
  }
}

// ---------------- LN stats: coalesced partial sums + atomics ----------------
__global__ __launch_bounds__(256) void ln_stats(
    const float* __restrict__ feat, float* __restrict__ sums)
{
  const int b = blockIdx.x, c0 = blockIdx.y * 128;
  const int l = threadIdx.x;
  if (l >= 192) return;
  const float* p = feat + ((size_t)b * 2048 + c0) * 192 + l;
  float s = 0.f, sq = 0.f;
  for (int c = 0; c < 128; ++c) { const float v = p[(size_t)c * 192]; s += v; sq = fmaf(v, v, sq); }
  atomicAdd(&sums[(b * 192 + l) * 2], s);
  atomicAdd(&sums[(b * 192 + l) * 2 + 1], sq);
}

// ---------------- LN apply + transpose -> bf16 fm (B*L, C) ----------------
__global__ __launch_bounds__(256) void ln_apply(
    const float* __restrict__ feat, const float* __restrict__ sums,
    const float* __restrict__ lnw, const float* __restrict__ lnb,
    ushort* __restrict__ fm)
{
  __shared__ float tile[64][65];
  __shared__ float smu[64], srs[64];
  const int b = blockIdx.x, c0 = blockIdx.y * 64, l0 = blockIdx.z * 64;
  const int tl = threadIdx.x & 63, tg = threadIdx.x >> 6;
#pragma unroll
  for (int r = 0; r < 16; ++r) {
    const int c = r * 4 + tg;
    tile[c][tl] = feat[((size_t)b * 2048 + c0 + c) * 192 + l0 + tl];
  }
  if (threadIdx.x < 64) {
    const float s  = sums[(b * 192 + l0 + threadIdx.x) * 2];
    const float sq = sums[(b * 192 + l0 + threadIdx.x) * 2 + 1];
    const float mu = s * (1.f / 2048.f);
    smu[threadIdx.x] = mu;
    srs[threadIdx.x] = rsqrtf(sq * (1.f / 2048.f) - mu * mu + EPSV);
  }
  __syncthreads();
  const float w = lnw[c0 + tl], bb = lnb[c0 + tl];
#pragma unroll
  for (int r = 0; r < 16; ++r) {
    const int ll = r * 4 + tg;
    fm[((size_t)(b * 192 + l0 + ll)) * 2048 + c0 + tl] =
        f2bf((tile[tl][ll] - smu[ll]) * srs[ll] * w + bb);
  }
}

// ---------------- MFMA K-phase: 128x128 tile, BK=32, 16x16x32 bf16 ----------
__device__ __forceinline__ void mfma_phase(
    const ushort* __restrict__ Ag, int lda,
    const ushort* __restrict__ Bg, int ldb, int K,
    int bm, int bn, int tid, ushort* As, ushort* Bs, f32x4 acc[4][4])
{
  const int lane = tid & 63, wave = tid >> 6;
  const int wm = (wave & 1) << 6, wn = (wave >> 1) << 6;
  const int fr = lane & 15, q = lane >> 4;
  const int r0 = tid >> 2, kc = (tid & 3) << 3;   // staging row / k-chunk
  const int lb = (tid & 192) * 8;                 // wave-uniform LDS base (ushorts)
  for (int k0 = 0; k0 < K; k0 += 32) {
    __syncthreads();
    GLOAD16(Ag + (size_t)(bm + r0) * lda + k0 + kc,      As + lb);
    GLOAD16(Ag + (size_t)(bm + 64 + r0) * lda + k0 + kc, As + 2048 + lb);
    GLOAD16(Bg + (size_t)(bn + r0) * ldb + k0 + kc,      Bs + lb);
    GLOAD16(Bg + (size_t)(bn + 64 + r0) * ldb + k0 + kc, Bs + 2048 + lb);
    __syncthreads();
    bf16x8 af[4], bfr[4];
#pragma unroll
    for (int i = 0; i < 4; ++i) {
      af[i]  = *(const bf16x8*)&As[(wm + i * 16 + fr) * 32 + q * 8];
      bfr[i] = *(const bf16x8*)&Bs[(wn + i * 16 + fr) * 32 + q * 8];
    }
#pragma unroll
    for (int i = 0; i < 4; ++i)
#pragma unroll
      for (int j = 0; j < 4; ++j)
        acc[i][j] = __builtin_amdgcn_mfma_f32_16x16x32_bf16(af[i], bfr[j], acc[i][j], 0, 0, 0);
  }
}

// MODE 0: out = A1*B1^T + bias(p0), fp32 row-major ldc=384.
// MODE 1: out = relu((A1*B1^T + A2*B2^T)*scale(p0) + shift(p1)), transposed store.
// MODE 2: outb = bf16(A1*B1^T), ldc=192, mask n<192 (W2 = mo_w @ out_w).
template<int MODE>
__global__ __launch_bounds__(256) void mfma_gemm(
    const ushort* __restrict__ A1, const ushort* __restrict__ B1,
    const ushort* __restrict__ A2, const ushort* __restrict__ B2,
    const float* __restrict__ p0, const float* __restrict__ p1,
    float* __restrict__ out, ushort* __restrict__ outb)
{
  __shared__ ushort As[4096], Bs[4096];
  const int tid = threadIdx.x;
  const int bm = blockIdx.y * 128, bn = blockIdx.x * 128;
  f32x4 acc[4][4];
#pragma unroll
  for (int i = 0; i < 4; ++i)
#pragma unroll
    for (int j = 0; j < 4; ++j) acc[i][j] = (f32x4)(0.f);

  mfma_phase(A1, 2048, B1, 2048, 2048, bm, bn, tid, As, Bs, acc);
  if (MODE == 1)
    mfma_phase(A2, 192, B2, 192, 192, bm, bn, tid, As, Bs, acc);

  const int lane = tid & 63, wave = tid >> 6;
  const int wm = (wave & 1) << 6, wn = (wave >> 1) << 6;
  const int fr = lane & 15, q = lane >> 4;
  if (MODE == 0) {
#pragma unroll
    for (int mi = 0; mi < 4; ++mi) {
      const int m0 = bm + wm + mi * 16 + q * 4;
#pragma unroll
      for (int ni = 0; ni < 4; ++ni) {
        const int n = bn + wn + ni * 16 + fr;
        const float bias = p0[n];
#pragma unroll
        for (int r = 0; r < 4; ++r)
          out[(size_t)(m0 + r) * 384 + n] = acc[mi][ni][r] + bias;
      }
    }
  } else if (MODE == 1) {
#pragma unroll
    for (int mi = 0; mi < 4; ++mi) {
      const int m0 = bm + wm + mi * 16 + q * 4;
      const int b = m0 / 192, l0 = m0 - b * 192;   // quad never straddles b
#pragma unroll
      for (int ni = 0; ni < 4; ++ni) {
        const int n = bn + wn + ni * 16 + fr;
        const float sc = p0[n], sh = p1[n];
        float4 o;
        o.x = fmaxf(fmaf(acc[mi][ni][0], sc, sh), 0.f);
        o.y = fmaxf(fmaf(acc[mi][ni][1], sc, sh), 0.f);
        o.z = fmaxf(fmaf(acc[mi][ni][2], sc, sh), 0.f);
        o.w = fmaxf(fmaf(acc[mi][ni][3], sc, sh), 0.f);
        *(float4*)(out + ((size_t)b * 2048 + n) * 192 + l0) = o;
      }
    }
  } else {
#pragma unroll
    for (int mi = 0; mi < 4; ++mi) {
      const int m0 = bm + wm + mi * 16 + q * 4;
#pragma unroll
      for (int ni = 0; ni < 4; ++ni) {
        const int n = bn + wn + ni * 16 + fr;
        if (n < 192) {
#pragma unroll
          for (int r = 0; r < 4; ++r)
            outb[(size_t)(m0 + r) * 192 + n] = f2bf(acc[mi][ni][r]);
        }
      }
    }
  }
}

// ---------------- x_proj + dt ----------------
__global__ __launch_bounds__(64) void xproj_kernel(
    const float* __restrict__ xz, const float* __restrict__ xpw,
    const float* __restrict__ dtw, float* __restrict__ dts,
    float* __restrict__ Bsb, float* __restrict__ Csb)
{
  const int m = blockIdx.x, tid = threadIdx.x;
  __shared__ float xrow[192];
  __shared__ float xdbl[38];
  const float* src = xz + (size_t)m * 384;
#pragma unroll
  for (int i = 0; i < 3; ++i) xrow[tid + i * 64] = src[tid + i * 64];
  __syncthreads();
  if (tid < 38) {
    float a = 0.f;
    const float* wr = xpw + tid * 192;
    for (int d = 0; d < 192; ++d) a = fmaf(xrow[d], wr[d], a);
    xdbl[tid] = a;
  }
  __syncthreads();
  if (tid < 16) Bsb[(size_t)m * 16 + tid] = xdbl[6 + tid];
  else if (tid < 32) Csb[(size_t)m * 16 + (tid - 16)] = xdbl[22 + (tid - 16)];
#pragma unroll
  for (int i = 0; i < 3; ++i) {
    const int d = tid + i * 64;
    const float* w = dtw + d * 6;
    float a = xdbl[0] * w[0] + xdbl[1] * w[1] + xdbl[2] * w[2]
            + xdbl[3] * w[3] + xdbl[4] * w[4] + xdbl[5] * w[5];
    dts[(size_t)m * 192 + d] = (a > 20.f) ? a : log1pf(__expf(a));
  }
}

// ---------------- bidirectional selective scan, LDS-staged -------------------
// grid = B * (192/16) = 768 blocks; 256 threads: lane = (dl = tid>>4, n = tid&15)
// Stages dt/x/B/C for the whole (b, 16-d) slice into LDS coalesced, then runs
// both scan directions out of LDS (broadcast reads, conflict-free), fused
// epilogue (yf+yb+2xD)*silu(z) -> bf16 ssm.
__global__ __launch_bounds__(256) void scan_kernel(
    const float* __restrict__ xz, const float* __restrict__ dts,
    const float* __restrict__ Bsb, const float* __restrict__ Csb,
    const float* __restrict__ A_logs, const float* __restrict__ Ds,
    ushort* __restrict__ ssm)
{
  __shared__ float s_dt[3072], s_x[3072], s_B[3072], s_C[3072], s_y[3072];
  const int tid = threadIdx.x;
  const int b = blockIdx.x / 12, dblk = blockIdx.x - b * 12;
  const int d0 = dblk * 16;
  const size_t rbase = (size_t)b * 192;
  // staging: 768 float4-groups per array, coalesced
  for (int i = tid; i < 768; i += 256) {
    const int l = i >> 2, j = (i & 3) << 2;
    const size_t row = rbase + l;
    ((float4*)s_dt)[i] = *(const float4*)(dts + row * 192 + d0 + j);
    ((float4*)s_x)[i]  = *(const float4*)(xz  + row * 384 + d0 + j);
    ((float4*)s_B)[i]  = *(const float4*)(Bsb + row * 16 + j);
    ((float4*)s_C)[i]  = *(const float4*)(Csb + row * 16 + j);
  }
  __syncthreads();
  const int n = tid & 15, dl = tid >> 4;
  const float Acoef = -expf(A_logs[(d0 + dl) * 16 + n]);
  float u = 0.f;
#pragma unroll 4
  for (int l = 0; l < 192; ++l) {
    const float dt = s_dt[l * 16 + dl];
    const float c  = dt * s_B[l * 16 + n] * s_x[l * 16 + dl];
    const float a  = __expf(dt * Acoef);
    u = fmaf(a, u, c);
    float y = u * s_C[l * 16 + n];
    y += __shfl_xor(y, 1, 16); y += __shfl_xor(y, 2, 16);
    y += __shfl_xor(y, 4, 16); y += __shfl_xor(y, 8, 16);
    if (n == 0) s_y[l * 16 + dl] = y;
  }
  u = 0.f;
#pragma unroll 4
  for (int l = 191; l >= 0; --l) {
    const float dt = s_dt[l * 16 + dl];
    const float c  = dt * s_B[l * 16 + n] * s_x[l * 16 + dl];
    const float a  = __expf(dt * Acoef);
    u = fmaf(a, u, c);
    float y = u * s_C[l * 16 + n];
    y += __shfl_xor(y, 1, 16); y += __shfl_xor(y, 2, 16);
    y += __shfl_xor(y, 4, 16); y += __shfl_xor(y, 8, 16);
    if (n == 0) s_y[l * 16 + dl] += y;   // same thread wrote fwd value: no race
  }
  __syncthreads();
  // epilogue: (yf+yb + 2*x*D) * silu(z) -> bf16
  for (int i = tid; i < 768; i += 256) {
    const int l = i >> 2, j = (i & 3) << 2;
    const size_t row = rbase + l;
    const float4 y4 = ((const float4*)s_y)[i];
    const float4 x4 = ((const float4*)s_x)[i];
    const float4 z4 = *(const float4*)(xz + row * 384 + 192 + d0 + j);
    const float4 D4 = *(const float4*)(Ds + d0 + j);
    ushort4 o;
    o.x = f2bf((y4.x + 2.f * x4.x * D4.x) * (z4.x / (1.f + __expf(-z4.x))));
    o.y = f2bf((y4.y + 2.f * x4.y * D4.y) * (z4.y / (1.f + __expf(-z4.y))));
    o.z = f2bf((y4.z + 2.f * x4.z * D4.z) * (z4.z / (1.f + __expf(-z4.z))));
    o.w = f2bf((y4.w + 2.f * x4.w * D4.w) * (z4.w / (1.f + __expf(-z4.w))));
    *(ushort4*)(ssm + row * 192 + d0 + j) = o;
  }
}

// ---------------- BN prep ----------------
__global__ __launch_bounds__(64) void prep_kernel(
    const float* __restrict__ mo_w, const float* __restrict__ mo_b,
    const float* __restrict__ out_b,
    const float* __restrict__ bn_w, const float* __restrict__ bn_b,
    const float* __restrict__ bn_rm, const float* __restrict__ bn_rv,
    float* __restrict__ scale, float* __restrict__ shift)
{
  const int o = blockIdx.x, tid = threadIdx.x;
  float s = 0.f;
  for (int c = tid; c < 2048; c += 64) s = fmaf(mo_w[(size_t)o * 2048 + c], out_b[c], s);
#pragma unroll
  for (int off = 32; off > 0; off >>= 1) s += __shfl_down(s, off, 64);
  if (tid == 0) {
    const float b2 = s + mo_b[o];
    const float sc = bn_w[o] * rsqrtf(bn_rv[o] + EPSV);
    scale[o] = sc;
    shift[o] = (b2 - bn_rm[o]) * sc + bn_b[o];
  }
}

extern "C" void kernel_launch(void* const* d_in, const int* in_sizes, int n_in,
                              void* d_out, int out_size, void* d_ws, size_t ws_size,
                              hipStream_t stream) {
  const float* feat  = (const float*)d_in[0];
  const float* ln_w  = (const float*)d_in[1];
  const float* ln_b  = (const float*)d_in[2];
  const float* in_w  = (const float*)d_in[3];
  const float* in_b  = (const float*)d_in[4];
  const float* xpw   = (const float*)d_in[5];
  const float* dtw   = (const float*)d_in[6];
  const float* A_logs= (const float*)d_in[7];
  const float* Ds    = (const float*)d_in[8];
  const float* out_w = (const float*)d_in[9];
  const float* out_b = (const float*)d_in[10];
  const float* mo_w  = (const float*)d_in[11];
  const float* mo_b  = (const float*)d_in[12];
  const float* bn_w  = (const float*)d_in[13];
  const float* bn_b  = (const float*)d_in[14];
  const float* bn_rm = (const float*)d_in[15];
  const float* bn_rv = (const float*)d_in[16];
  float* out = (float*)d_out;

  // ---- workspace layout (bytes) ----
  uint8_t* p = (uint8_t*)d_ws;
  ushort* fm_b  = (ushort*)p; p += (size_t)12288 * 2048 * 2;  // 50331648
  float*  xz    = (float*)p;  p += (size_t)12288 * 384 * 4;   // 18874368
  float*  dts   = (float*)p;  p += (size_t)12288 * 192 * 4;   // 9437184
  float*  Bsb   = (float*)p;  p += (size_t)12288 * 16 * 4;    // 786432
  float*  Csb   = (float*)p;  p += (size_t)12288 * 16 * 4;    // 786432
  ushort* ssm_b = (ushort*)p; p += (size_t)12288 * 192 * 2;   // 4718592
  ushort* W2b   = (ushort*)p; p += (size_t)2048 * 192 * 2;    // 786432
  ushort* owT_b = (ushort*)p; p += (size_t)256 * 2048 * 2;    // 1048576 (padded)
  ushort* mo_wb = (ushort*)p; p += (size_t)2048 * 2048 * 2;   // 8388608
  ushort* in_wb = (ushort*)p; p += (size_t)384 * 2048 * 2;    // 1572864
  float*  scale = (float*)p;  p += 2048 * 4;
  float*  shift = (float*)p;  p += 2048 * 4;
  float*  sums  = (float*)p;  p += (size_t)64 * 192 * 2 * 4;  // 98304
  if ((size_t)(p - (uint8_t*)d_ws) > ws_size) return;

  // weights -> bf16 (+ padded transpose of out_w)
  cvt_kernel<<<4096, 256, 0, stream>>>(mo_w, mo_wb, 2048 * 2048);
  cvt_kernel<<<768, 256, 0, stream>>>(in_w, in_wb, 384 * 2048);
  hipMemsetAsync(owT_b, 0, (size_t)256 * 2048 * 2, stream);
  transpose_w<<<dim3(32, 3), 256, 0, stream>>>(out_w, owT_b);

  // LN (stats + apply/transpose -> bf16 fm)
  hipMemsetAsync(sums, 0, (size_t)64 * 192 * 2 * 4, stream);
  ln_stats<<<dim3(64, 16), 256, 0, stream>>>(feat, sums);
  ln_apply<<<dim3(64, 32, 3), 256, 0, stream>>>(feat, sums, ln_w, ln_b, fm_b);

  // GEMM1: xz = fm @ in_w^T + in_b   (M=12288, N=384, K=2048)
  mfma_gemm<0><<<dim3(3, 96), 256, 0, stream>>>(
      fm_b, in_wb, nullptr, nullptr, in_b, nullptr, xz, nullptr);

  xproj_kernel<<<12288, 64, 0, stream>>>(xz, xpw, dtw, dts, Bsb, Csb);
  scan_kernel<<<768, 256, 0, stream>>>(xz, dts, Bsb, Csb, A_logs, Ds, ssm_b);

  // W2 = bf16(mo_w @ out_w)  (M=2048, N=192 padded to 256, K=2048)
  mfma_gemm<2><<<dim3(2, 16), 256, 0, stream>>>(
      mo_wb, owT_b, nullptr, nullptr, nullptr, nullptr, nullptr, W2b);
  prep_kernel<<<2048, 64, 0, stream>>>(mo_w, mo_b, out_b, bn_w, bn_b, bn_rm, bn_rv, scale, shift);

  // Final: out = relu(bn(fm@mo_w^T + ssm@W2^T)), transposed store
  mfma_gemm<1><<<dim3(16, 96), 256, 0, stream>>>(
      fm_b, mo_wb, ssm_b, W2b, scale, shift, out, nullptr);
}